// Round 3
// baseline (285.352 us; speedup 1.0000x reference)
//
#include <hip/hip_runtime.h>
#include <math.h>

// FNO1d via fp16 MFMA, round 8: occupancy push via LDS diet.
// - HO_S 136->132, MS_S/BI_S 40->36 (bank-uniformity hand-verified: all
//   64-lane b128 patterns stay uniform across 32 banks at the new strides).
// - BasF aliased into the pool (Hout 16896 + BasF 8704 = 25600 = pool size);
//   staged AFTER the pre-epilogue barrier (Ht/Ws dead), loads hidden under
//   the GELU VALU work.
// - layer LDS 50176 -> 39680 B => 4 blocks/CU (was 3); launch_bounds(256,4).
// - lift LDS 26112 -> 25600 B => 6 blocks/CU by LDS; launch_bounds(256,5).
// Carried from R7: parallel mode_mix w/ in-place S zeroing (no memsets),
// A&S-7.1.26 branchless GELU, role-swapped GEMM, in-register 8x8 v_perm
// transpose staging with XOR bank swizzle, cvt_pkrtz packed epilogue.
// MFMA layouts (m89/m91): A[m=lane&15][k=quad*8+j], B[k=quad*8+j][n=lane&15],
// C/D col=lane&15, row=quad*4+reg.

typedef _Float16 f16;
typedef _Float16 f16x2 __attribute__((ext_vector_type(2)));
typedef _Float16 f16x4 __attribute__((ext_vector_type(4)));
typedef _Float16 f16x8 __attribute__((ext_vector_type(8)));
typedef float    f32x2 __attribute__((ext_vector_type(2)));
typedef float    f32x4 __attribute__((ext_vector_type(4)));
typedef unsigned int u32;

#define BB 64
#define NN 8192

#define HT_S 64    // Ht [n=128][i=64], XOR-swizzled, stride 64 (no pad)
#define HO_S 132   // Hout [o=64][n=128]  (stride 264 B: bank-uniform)
#define WS_S 72    // Ws [o=64][i=64]
#define MS_S 36    // Ms2 [o=64][j=32]
#define BI_S 36    // BasI [n=128][j=32]
#define BF_S 136   // BasF [km=32][n=128]

// swizzle group for Ht row n
__device__ __forceinline__ int ht_swz(int n) { return ((n & 7) ^ ((n >> 3) & 7)) << 3; }

// Branchless GELU: 0.5*v*(1+erf(v/sqrt(2))) with A&S 7.1.26 erf, |err|<=1.5e-7.
__device__ __forceinline__ float gelu_f(float v) {
    float x  = v * 0.70710678118654752f;
    float ax = fabsf(x);
    float t  = __builtin_amdgcn_rcpf(fmaf(0.3275911f, ax, 1.0f));
    float p  = fmaf(1.061405429f, t, -1.453152027f);
    p = fmaf(p, t, 1.421413741f);
    p = fmaf(p, t, -0.284496736f);
    p = fmaf(p, t, 0.254829592f);
    p = p * t;
    float e  = __expf(-x * x);
    float er = fmaf(-p, e, 1.0f);     // erf(|x|)
    er = copysignf(er, x);
    return 0.5f * fmaf(v, er, v);
}

// ---------------------------------------------------------------- prep
// BasF[k][n]=cos(2pi k n/N), BasF[16+k][n]=-sin; BasI[n][2k]=cos,[2k+1]=sin
// Also converts w_w (4*64*64) to fp16 and zeroes S (131072 floats).
__global__ __launch_bounds__(256) void fill_basis(f16* __restrict__ basF,
                                                  f16* __restrict__ basI,
                                                  const float* __restrict__ w_w,
                                                  f16* __restrict__ Wh,
                                                  float* __restrict__ Sz) {
    int n = blockIdx.x * 256 + threadIdx.x;   // 0..8191
    f16 row[32];
#pragma unroll
    for (int k = 0; k < 16; ++k) {
        float s, c;
        sincospif((float)(k * n) * (1.0f / 4096.0f), &s, &c);
        basF[k * NN + n]        = (f16)c;
        basF[(16 + k) * NN + n] = (f16)(-s);
        row[2 * k]     = (f16)c;
        row[2 * k + 1] = (f16)s;
    }
#pragma unroll
    for (int q = 0; q < 4; ++q) *(f16x8*)&basI[n * 32 + 8 * q] = *(f16x8*)&row[8 * q];
    Wh[n]        = (f16)w_w[n];
    Wh[n + 8192] = (f16)w_w[n + 8192];
    // zero S: 131072 floats / 8192 threads = 4 f32x4 each
    f32x4* S4 = (f32x4*)Sz;
    f32x4 z = {0.f, 0.f, 0.f, 0.f};
#pragma unroll
    for (int u = 0; u < 4; ++u) S4[n * 4 + u] = z;
}

// ---------------------------------------------------------------- mode mixing
// S[b][km 32][i 64] (km<16 Re, >=16 Im) -> Mph fp16 pre-scaled:
// Mph[b][o][2k]=sck*(Re.wr - Im.wi), [2k+1]=-sck*(Re.wi + Im.wr)
// Grid BB, 1024 threads; block b is the SOLE reader of S[b], so after staging
// to LDS it re-zeroes S[b] in place for the next layer's atomics (no memset).
__global__ __launch_bounds__(1024) void mode_mix(float* __restrict__ S,
                                                 const float* __restrict__ wr,
                                                 const float* __restrict__ wi,
                                                 f16* __restrict__ Mph) {
    int b = blockIdx.x, t = threadIdx.x;
    __shared__ float Ss[32 * 66];
    if (t < 512) {
        f32x4 v = *(const f32x4*)&S[b * 2048 + t * 4];
        int rw = t >> 4, cl = (t & 15) * 4;
#pragma unroll
        for (int e = 0; e < 4; ++e) Ss[rw * 66 + cl + e] = v[e];
    }
    __syncthreads();
    // zero S[b] for the next layer's atomicAdd accumulation
    *(f32x2*)&S[b * 2048 + t * 2] = (f32x2){0.f, 0.f};

    int o = t >> 4, k = t & 15;
    const float* wrp = wr + o * 16 + k;
    const float* wip = wi + o * 16 + k;
    float ar = 0.f, ai = 0.f;
#pragma unroll 8
    for (int i = 0; i < 64; ++i) {
        float sr = Ss[k * 66 + i], si = Ss[(16 + k) * 66 + i];
        float wrv = wrp[i * 1024];
        float wiv = wip[i * 1024];
        ar = fmaf(sr, wrv, ar); ar = fmaf(-si, wiv, ar);
        ai = fmaf(sr, wiv, ai); ai = fmaf(si, wrv, ai);
    }
    float sc = (k == 0 ? 1.0f : 2.0f) * (1.0f / 8192.0f);
    f16x2 outv = { (f16)(sc * ar), (f16)(-sc * ai) };
    *(f16x2*)&Mph[b * 2048 + o * 32 + 2 * k] = outv;
}

// ---------------------------------------------------------------- DFT epilogue
// S[b][km][i] += BasF[km][n] . Hout[i][n]  over this block's 128-n tile
__device__ __forceinline__ void dft_epilogue(const f16* Hout, const f16* BasF,
                                             float* __restrict__ S, int b,
                                             int lane, int wv) {
    int q = lane >> 4, l15 = lane & 15;
    f32x4 sacc[2] = {{0.f,0.f,0.f,0.f},{0.f,0.f,0.f,0.f}};
#pragma unroll
    for (int ks = 0; ks < 4; ++ks) {
        int o = (wv << 4) + l15;
        f16x8 bh = *(const f16x8*)&Hout[o * HO_S + ks * 32 + q * 8];
#pragma unroll
        for (int mt = 0; mt < 2; ++mt) {
            f16x8 af = *(const f16x8*)&BasF[(mt * 16 + l15) * BF_S + ks * 32 + q * 8];
            sacc[mt] = __builtin_amdgcn_mfma_f32_16x16x32_f16(af, bh, sacc[mt], 0, 0, 0);
        }
    }
#pragma unroll
    for (int mt = 0; mt < 2; ++mt)
#pragma unroll
        for (int r = 0; r < 4; ++r)
            atomicAdd(&S[(b * 32 + mt * 16 + q * 4 + r) * 64 + (wv << 4) + l15],
                      sacc[mt][r]);
}

// ---------------------------------------------------------------- lifting (+DFT)
__global__ __launch_bounds__(256, 5) void lift_kernel(const float* __restrict__ x,
                                                      const float* __restrict__ p_w,
                                                      const float* __restrict__ p_b,
                                                      f16* __restrict__ h,
                                                      const f16* __restrict__ basF_g,
                                                      float* __restrict__ S) {
    __shared__ f16 Hout[64 * HO_S];
    __shared__ f16 BasF[32 * BF_S];
    int t = threadIdx.x;
    int b = blockIdx.x >> 6;
    int n0 = (blockIdx.x & 63) << 7;
#pragma unroll
    for (int r = 0; r < 4; ++r) {
        int o = (t >> 4) + 16 * r;
        int ns = (t & 15) << 3;
        float w0 = p_w[2 * o], w1 = p_w[2 * o + 1], pb = p_b[o];
        f16 vals[8];
#pragma unroll
        for (int j = 0; j < 8; ++j) {
            int n = n0 + ns + j;
            float xv = x[(b << 13) + n];
            vals[j] = (f16)(w0 * xv + w1 * ((float)n * (1.0f / 8191.0f)) + pb);
        }
        *(f16x8*)&Hout[o * HO_S + ns] = *(f16x8*)vals;
        *(f16x8*)(h + (((size_t)(b * 64 + o)) << 13) + n0 + ns) = *(f16x8*)vals;
    }
#pragma unroll
    for (int u = 0; u < 2; ++u) {
        int km = t >> 3, nn = (t & 7) * 16 + u * 8;
        *(f16x8*)&BasF[km * BF_S + nn] = *(const f16x8*)&basF_g[km * NN + n0 + nn];
    }
    __syncthreads();
    dft_epilogue(Hout, BasF, S, b, t & 63, t >> 6);
}

// ---------------------------------------------------------------- fused layer
// DO_DFT=1: layers 0..2 (write h + accumulate S). DO_DFT=0: layer 3 (proj)
template <int DO_DFT>
__global__ __launch_bounds__(256, 4) void layer_kernel(f16* __restrict__ h,
                                                       const f16* __restrict__ Wl_h,
                                                       const float* __restrict__ bl,
                                                       const f16* __restrict__ Mph,
                                                       const f16* __restrict__ basF_g,
                                                       const f16* __restrict__ basI_g,
                                                       float* __restrict__ S,
                                                       const float* __restrict__ q_w,
                                                       const float* __restrict__ q_b,
                                                       float* __restrict__ out) {
    // pool phase 1: Ht 128*64*2=16384 B + Ws 64*72*2=9216 B  (= 25600 B)
    // pool phase 2: Hout 64*132*2=16896 B + BasF 32*136*2=8704 B (= 25600 B)
    __shared__ __align__(16) char pool[25600];
    f16* Ht    = (f16*)pool;
    f16* Ws    = (f16*)(pool + 16384);
    f16* Hout  = (f16*)pool;
    f16* BasFp = (f16*)(pool + 16896);
    __shared__ f16 Ms2[64 * MS_S];
    __shared__ f16 BasI[128 * BI_S];
    __shared__ float bls[64];
    int t = threadIdx.x;
    int b = blockIdx.x >> 6;
    int n0 = (blockIdx.x & 63) << 7;
    f16* hb = h + (((size_t)(b * 64)) << 13) + n0;

    if (t < 128) {
        // ---- transpose-stage Ht[n][i] from global h[i][n] (8x8 blocks)
        int ig = t >> 4, nb = t & 15;       // i0 = ig*8, ns = nb*8
        int i0 = ig << 3, ns = nb << 3;
        f16x8 R[8];
#pragma unroll
        for (int k = 0; k < 8; ++k)
            R[k] = *(const f16x8*)(hb + ((size_t)(i0 + k) << 13) + ns);
        const u32* rd = (const u32*)R;      // rd[k*4 + d]
        int swz = nb & 7;
#pragma unroll
        for (int j = 0; j < 8; ++j) {
            u32 o[4] __attribute__((aligned(16)));
            u32 sel = (j & 1) ? 0x07060302u : 0x05040100u;
            int jd = j >> 1;
#pragma unroll
            for (int e = 0; e < 4; ++e)
                o[e] = __builtin_amdgcn_perm(rd[(2 * e + 1) * 4 + jd],
                                             rd[(2 * e) * 4 + jd], sel);
            int col = i0 ^ ((j ^ swz) << 3);
            *(f16x8*)&Ht[(ns + j) * HT_S + col] = *(const f16x8*)o;
        }
    } else {
        int t2 = t - 128;
        // ---- Ws [o][i] fp16 (pre-converted): 32 halfs per thread
        {
            int o = t2 & 63, hs = (t2 >> 6) * 32;
            const f16* src = Wl_h + o * 64 + hs;
            f16* dst = &Ws[o * WS_S + hs];
#pragma unroll
            for (int u = 0; u < 4; ++u) *(f16x8*)&dst[8 * u] = *(const f16x8*)&src[8 * u];
        }
        // ---- Ms2 [o][j]: 16 halfs per thread
        {
            int o = t2 >> 1, seg = (t2 & 1) * 16;
            const f16* src = Mph + b * 2048 + o * 32 + seg;
            f16* dst = &Ms2[o * MS_S + seg];
            *(f16x8*)&dst[0] = *(const f16x8*)&src[0];
            *(f16x8*)&dst[8] = *(const f16x8*)&src[8];
        }
        // ---- BasI [n][j]: one row per thread
        {
            const f16* src = basI_g + (size_t)(n0 + t2) * 32;
            f16* dst = &BasI[t2 * BI_S];
#pragma unroll
            for (int u = 0; u < 4; ++u) *(f16x8*)&dst[8 * u] = *(const f16x8*)&src[8 * u];
        }
    }
    if (t < 64) bls[t] = bl[t];
    __syncthreads();

    int lane = t & 63, wv = t >> 6;
    int q = lane >> 4, l15 = lane & 15;

    // ---- B-frags: Ws (conv) and Ms2 (irfft)
    f16x8 Bw[4][2], Bm[4];
#pragma unroll
    for (int ct = 0; ct < 4; ++ct) {
#pragma unroll
        for (int ks = 0; ks < 2; ++ks)
            Bw[ct][ks] = *(const f16x8*)&Ws[(ct * 16 + l15) * WS_S + ks * 32 + q * 8];
        Bm[ct] = *(const f16x8*)&Ms2[(ct * 16 + l15) * MS_S + q * 8];
    }

    f32x4 acc[4][2];   // [ct(o-tile)][mtl(n-tile)]
#pragma unroll
    for (int ct = 0; ct < 4; ++ct)
#pragma unroll
        for (int m = 0; m < 2; ++m) acc[ct][m] = (f32x4){0.f, 0.f, 0.f, 0.f};

#pragma unroll
    for (int mtl = 0; mtl < 2; ++mtl) {
        int nrow = (2 * wv + mtl) * 16 + l15;
        const f16* hrow = &Ht[nrow * HT_S];
        int g3 = ht_swz(nrow);
        // conv: D[n][o] += h^T[n][i] . W[o][i], K=64
#pragma unroll
        for (int ks = 0; ks < 2; ++ks) {
            f16x8 Ah = *(const f16x8*)&hrow[(ks * 32 + q * 8) ^ g3];
#pragma unroll
            for (int ct = 0; ct < 4; ++ct)
                acc[ct][mtl] = __builtin_amdgcn_mfma_f32_16x16x32_f16(
                    Ah, Bw[ct][ks], acc[ct][mtl], 0, 0, 0);
        }
        // irfft: D[n][o] += BasI[n][j] . Ms2[o][j], K=32
        f16x8 Ab = *(const f16x8*)&BasI[nrow * BI_S + q * 8];
#pragma unroll
        for (int ct = 0; ct < 4; ++ct)
            acc[ct][mtl] = __builtin_amdgcn_mfma_f32_16x16x32_f16(
                Ab, Bm[ct], acc[ct][mtl], 0, 0, 0);
    }

    // ---- epilogue: bias + fast exact-erf GELU -> Hout[o][n] fp16 (aliases Ht)
    float bv[4];
#pragma unroll
    for (int ct = 0; ct < 4; ++ct) bv[ct] = bls[ct * 16 + l15];
    __syncthreads();   // all Ht/Ws reads complete before overwrite

    // stage BasF into pool (Ws region, now dead); loads hide under GELU VALU
    if (DO_DFT) {
#pragma unroll
        for (int u = 0; u < 2; ++u) {
            int g = t + 256 * u;            // 0..511 = 32 rows x 16 vecs
            int row = g >> 4, col = (g & 15) * 8;
            *(f16x8*)&BasFp[row * BF_S + col] =
                *(const f16x8*)&basF_g[row * NN + n0 + col];
        }
    }
#pragma unroll
    for (int ct = 0; ct < 4; ++ct) {
        int o = ct * 16 + l15;
#pragma unroll
        for (int mtl = 0; mtl < 2; ++mtl) {
            int nbase = (2 * wv + mtl) * 16 + q * 4;
            float g[4];
#pragma unroll
            for (int r = 0; r < 4; ++r)
                g[r] = gelu_f(acc[ct][mtl][r] + bv[ct]);
            f16x2 lo = __builtin_bit_cast(f16x2, __builtin_amdgcn_cvt_pkrtz(g[0], g[1]));
            f16x2 hi = __builtin_bit_cast(f16x2, __builtin_amdgcn_cvt_pkrtz(g[2], g[3]));
            f16x4 pk = {lo[0], lo[1], hi[0], hi[1]};
            *(f16x4*)&Hout[o * HO_S + nbase] = pk;
        }
    }
    __syncthreads();

    if (DO_DFT) {
        dft_epilogue(Hout, BasFp, S, b, lane, wv);
        // ---- store h tile (coalesced b128)
#pragma unroll
        for (int r = 0; r < 4; ++r) {
            int o = (t >> 4) + 16 * r;
            int ns = (t & 15) << 3;
            *(f16x8*)(hb + ((size_t)o << 13) + ns) = *(f16x8*)&Hout[o * HO_S + ns];
        }
    } else {
        // ---- projection: out[b][n] = q_b + sum_o q_w[o]*h[o][n]
        if (t < 128) {
            int n = t;
            float s = q_b[0];
#pragma unroll 8
            for (int o = 0; o < 64; ++o) s += q_w[o] * (float)Hout[o * HO_S + n];
            out[(b << 13) + n0 + n] = s;
        }
    }
}

// ---------------------------------------------------------------- launch
extern "C" void kernel_launch(void* const* d_in, const int* in_sizes, int n_in,
                              void* d_out, int out_size, void* d_ws, size_t ws_size,
                              hipStream_t stream) {
    const float* x     = (const float*)d_in[0];
    const float* p_w   = (const float*)d_in[1];
    const float* p_b   = (const float*)d_in[2];
    const float* sc_wr = (const float*)d_in[3];
    const float* sc_wi = (const float*)d_in[4];
    const float* w_w   = (const float*)d_in[5];
    const float* w_b   = (const float*)d_in[6];
    const float* q_w   = (const float*)d_in[7];
    const float* q_b   = (const float*)d_in[8];
    float* out = (float*)d_out;

    char* ws = (char*)d_ws;
    f16*   h    = (f16*)ws;                               // 67,108,864 B
    float* S    = (float*)(ws + 67108864ull);             // 524,288 B
    f16*   Mph  = (f16*)(ws + 67633152ull);               // 262,144 B
    f16*   basF = (f16*)(ws + 67895296ull);               // 524,288 B
    f16*   basI = (f16*)(ws + 68419584ull);               // 524,288 B
    f16*   Wh   = (f16*)(ws + 68943872ull);               // 32,768 B

    hipLaunchKernelGGL(fill_basis, dim3(NN / 256), dim3(256), 0, stream,
                       basF, basI, w_w, Wh, S);
    hipLaunchKernelGGL(lift_kernel, dim3(BB * 64), dim3(256), 0, stream,
                       x, p_w, p_b, h, basF, S);
    for (int l = 0; l < 4; ++l) {
        hipLaunchKernelGGL(mode_mix, dim3(BB), dim3(1024), 0, stream,
                           S, sc_wr + l * 65536, sc_wi + l * 65536, Mph);
        if (l < 3) {
            hipLaunchKernelGGL((layer_kernel<1>), dim3(BB * 64), dim3(256), 0, stream,
                               h, Wh + l * 4096, w_b + l * 64, Mph, basF, basI, S,
                               q_w, q_b, out);
        } else {
            hipLaunchKernelGGL((layer_kernel<0>), dim3(BB * 64), dim3(256), 0, stream,
                               h, Wh + l * 4096, w_b + l * 64, Mph, basF, basI, S,
                               q_w, q_b, out);
        }
    }
}

// Round 4
// 262.196 us; speedup vs baseline: 1.0883x; 1.0883x over previous
//
#include <hip/hip_runtime.h>
#include <math.h>

// FNO1d via fp16 MFMA, round 9:
// - REVERT R8's LDS diet (it regressed layer 46->55 us despite occupancy
//   +9pts: kernel is latency-bound, not residency-bound). Back to R7-proven
//   HO_S 136 / MS_S,BI_S 40 / upfront BasF / launch_bounds(256,3).
// - NEW: 2-tile blocks for lift + layer<1>. Each block owns 256 n; DFT
//   partial sums accumulate in registers (sacc) across both tiles and flush
//   atomics ONCE -> memory-side atomic RMW traffic and same-line contention
//   halve (8.4M -> 4.2M ops; FETCH -17MB, WRITE -17MB predicted).
//   B-frags (Bw/Bm) are register-resident across tiles, so the Ht/Hout pool
//   aliasing stays safe. TILES=2 keeps 8 blocks/CU scheduling granularity.
// Carried from R7: parallel mode_mix w/ in-place S zeroing (no memsets),
// A&S-7.1.26 branchless GELU, role-swapped GEMM, in-register 8x8 v_perm
// transpose staging with XOR bank swizzle, cvt_pkrtz packed epilogue.
// MFMA layouts (m89/m91): A[m=lane&15][k=quad*8+j], B[k=quad*8+j][n=lane&15],
// C/D col=lane&15, row=quad*4+reg.

typedef _Float16 f16;
typedef _Float16 f16x2 __attribute__((ext_vector_type(2)));
typedef _Float16 f16x4 __attribute__((ext_vector_type(4)));
typedef _Float16 f16x8 __attribute__((ext_vector_type(8)));
typedef float    f32x2 __attribute__((ext_vector_type(2)));
typedef float    f32x4 __attribute__((ext_vector_type(4)));
typedef unsigned int u32;

#define BB 64
#define NN 8192

#define HT_S 64    // Ht [n=128][i=64], XOR-swizzled, stride 64 (no pad)
#define HO_S 136   // Hout [o=64][n=128]
#define WS_S 72    // Ws [o=64][i=64]
#define MS_S 40    // Ms2 [o=64][j=32]
#define BI_S 40    // BasI [n=128][j=32]
#define BF_S 136   // BasF [km=32][n=128]

// swizzle group for Ht row n
__device__ __forceinline__ int ht_swz(int n) { return ((n & 7) ^ ((n >> 3) & 7)) << 3; }

// Branchless GELU: 0.5*v*(1+erf(v/sqrt(2))) with A&S 7.1.26 erf, |err|<=1.5e-7.
__device__ __forceinline__ float gelu_f(float v) {
    float x  = v * 0.70710678118654752f;
    float ax = fabsf(x);
    float t  = __builtin_amdgcn_rcpf(fmaf(0.3275911f, ax, 1.0f));
    float p  = fmaf(1.061405429f, t, -1.453152027f);
    p = fmaf(p, t, 1.421413741f);
    p = fmaf(p, t, -0.284496736f);
    p = fmaf(p, t, 0.254829592f);
    p = p * t;
    float e  = __expf(-x * x);
    float er = fmaf(-p, e, 1.0f);     // erf(|x|)
    er = copysignf(er, x);
    return 0.5f * fmaf(v, er, v);
}

// ---------------------------------------------------------------- prep
__global__ __launch_bounds__(256) void fill_basis(f16* __restrict__ basF,
                                                  f16* __restrict__ basI,
                                                  const float* __restrict__ w_w,
                                                  f16* __restrict__ Wh,
                                                  float* __restrict__ Sz) {
    int n = blockIdx.x * 256 + threadIdx.x;   // 0..8191
    f16 row[32];
#pragma unroll
    for (int k = 0; k < 16; ++k) {
        float s, c;
        sincospif((float)(k * n) * (1.0f / 4096.0f), &s, &c);
        basF[k * NN + n]        = (f16)c;
        basF[(16 + k) * NN + n] = (f16)(-s);
        row[2 * k]     = (f16)c;
        row[2 * k + 1] = (f16)s;
    }
#pragma unroll
    for (int q = 0; q < 4; ++q) *(f16x8*)&basI[n * 32 + 8 * q] = *(f16x8*)&row[8 * q];
    Wh[n]        = (f16)w_w[n];
    Wh[n + 8192] = (f16)w_w[n + 8192];
    // zero S: 131072 floats / 8192 threads = 4 f32x4 each
    f32x4* S4 = (f32x4*)Sz;
    f32x4 z = {0.f, 0.f, 0.f, 0.f};
#pragma unroll
    for (int u = 0; u < 4; ++u) S4[n * 4 + u] = z;
}

// ---------------------------------------------------------------- mode mixing
// Grid BB, 1024 threads; block b is the SOLE reader of S[b], so after staging
// to LDS it re-zeroes S[b] in place for the next layer's atomics (no memset).
__global__ __launch_bounds__(1024) void mode_mix(float* __restrict__ S,
                                                 const float* __restrict__ wr,
                                                 const float* __restrict__ wi,
                                                 f16* __restrict__ Mph) {
    int b = blockIdx.x, t = threadIdx.x;
    __shared__ float Ss[32 * 66];
    if (t < 512) {
        f32x4 v = *(const f32x4*)&S[b * 2048 + t * 4];
        int rw = t >> 4, cl = (t & 15) * 4;
#pragma unroll
        for (int e = 0; e < 4; ++e) Ss[rw * 66 + cl + e] = v[e];
    }
    __syncthreads();
    // zero S[b] for the next layer's atomicAdd accumulation
    *(f32x2*)&S[b * 2048 + t * 2] = (f32x2){0.f, 0.f};

    int o = t >> 4, k = t & 15;
    const float* wrp = wr + o * 16 + k;
    const float* wip = wi + o * 16 + k;
    float ar = 0.f, ai = 0.f;
#pragma unroll 8
    for (int i = 0; i < 64; ++i) {
        float sr = Ss[k * 66 + i], si = Ss[(16 + k) * 66 + i];
        float wrv = wrp[i * 1024];
        float wiv = wip[i * 1024];
        ar = fmaf(sr, wrv, ar); ar = fmaf(-si, wiv, ar);
        ai = fmaf(sr, wiv, ai); ai = fmaf(si, wrv, ai);
    }
    float sc = (k == 0 ? 1.0f : 2.0f) * (1.0f / 8192.0f);
    f16x2 outv = { (f16)(sc * ar), (f16)(-sc * ai) };
    *(f16x2*)&Mph[b * 2048 + o * 32 + 2 * k] = outv;
}

// ---------------------------------------------------------------- DFT pieces
// sacc[mt] += BasF[mt*16+l15][n-tile] . Hout[o][n-tile]  (register accumulate)
__device__ __forceinline__ void dft_accum(const f16* Hout, const f16* BasF,
                                          f32x4 sacc[2], int lane, int wv) {
    int q = lane >> 4, l15 = lane & 15;
    int o = (wv << 4) + l15;
#pragma unroll
    for (int ks = 0; ks < 4; ++ks) {
        f16x8 bh = *(const f16x8*)&Hout[o * HO_S + ks * 32 + q * 8];
#pragma unroll
        for (int mt = 0; mt < 2; ++mt) {
            f16x8 af = *(const f16x8*)&BasF[(mt * 16 + l15) * BF_S + ks * 32 + q * 8];
            sacc[mt] = __builtin_amdgcn_mfma_f32_16x16x32_f16(af, bh, sacc[mt], 0, 0, 0);
        }
    }
}

__device__ __forceinline__ void dft_flush(const f32x4 sacc[2], float* __restrict__ S,
                                          int b, int lane, int wv) {
    int q = lane >> 4, l15 = lane & 15;
#pragma unroll
    for (int mt = 0; mt < 2; ++mt)
#pragma unroll
        for (int r = 0; r < 4; ++r)
            atomicAdd(&S[(b * 32 + mt * 16 + q * 4 + r) * 64 + (wv << 4) + l15],
                      sacc[mt][r]);
}

// ---------------------------------------------------------------- lifting (+DFT)
// Grid BB*32; each block owns 2 n-tiles (256 n), flushes atomics once.
__global__ __launch_bounds__(256, 3) void lift_kernel(const float* __restrict__ x,
                                                      const float* __restrict__ p_w,
                                                      const float* __restrict__ p_b,
                                                      f16* __restrict__ h,
                                                      const f16* __restrict__ basF_g,
                                                      float* __restrict__ S) {
    __shared__ f16 Hout[64 * HO_S];
    __shared__ f16 BasF[32 * BF_S];
    int t = threadIdx.x;
    int b = blockIdx.x >> 5;
    int g = blockIdx.x & 31;
    int lane = t & 63, wv = t >> 6;

    float w0[4], w1[4], pb[4];
#pragma unroll
    for (int r = 0; r < 4; ++r) {
        int o = (t >> 4) + 16 * r;
        w0[r] = p_w[2 * o]; w1[r] = p_w[2 * o + 1]; pb[r] = p_b[o];
    }

    f32x4 sacc[2] = {{0.f,0.f,0.f,0.f},{0.f,0.f,0.f,0.f}};
#pragma unroll
    for (int tile = 0; tile < 2; ++tile) {
        int n0 = ((g << 1) + tile) << 7;
#pragma unroll
        for (int r = 0; r < 4; ++r) {
            int o = (t >> 4) + 16 * r;
            int ns = (t & 15) << 3;
            f16 vals[8];
#pragma unroll
            for (int j = 0; j < 8; ++j) {
                int n = n0 + ns + j;
                float xv = x[(b << 13) + n];
                vals[j] = (f16)(w0[r] * xv + w1[r] * ((float)n * (1.0f / 8191.0f)) + pb[r]);
            }
            *(f16x8*)&Hout[o * HO_S + ns] = *(f16x8*)vals;
            *(f16x8*)(h + (((size_t)(b * 64 + o)) << 13) + n0 + ns) = *(f16x8*)vals;
        }
#pragma unroll
        for (int u = 0; u < 2; ++u) {
            int km = t >> 3, nn = (t & 7) * 16 + u * 8;
            *(f16x8*)&BasF[km * BF_S + nn] = *(const f16x8*)&basF_g[km * NN + n0 + nn];
        }
        __syncthreads();
        dft_accum(Hout, BasF, sacc, lane, wv);
        if (tile == 0) __syncthreads();   // Hout/BasF reads done before restage
    }
    dft_flush(sacc, S, b, lane, wv);
}

// ---------------------------------------------------------------- fused layer
// DO_DFT=1: layers 0..2, 2 n-tiles/block (grid BB*32), atomics flushed once.
// DO_DFT=0: layer 3 (projection), 1 tile/block (grid BB*64).
template <int DO_DFT>
__global__ __launch_bounds__(256, 3) void layer_kernel(f16* __restrict__ h,
                                                       const f16* __restrict__ Wl_h,
                                                       const float* __restrict__ bl,
                                                       const f16* __restrict__ Mph,
                                                       const f16* __restrict__ basF_g,
                                                       const f16* __restrict__ basI_g,
                                                       float* __restrict__ S,
                                                       const float* __restrict__ q_w,
                                                       const float* __restrict__ q_b,
                                                       float* __restrict__ out) {
    constexpr int TILES = DO_DFT ? 2 : 1;
    constexpr int GPB   = 64 / TILES;   // n-tile groups per batch
    // pool phase 1: Ht 128*64*2=16384 B + Ws 64*72*2=9216 B
    // pool phase 2: Hout 64*136*2=17408 B (spills 1KB into Ws -- safe: Ws is
    // register-resident as Bw frags before first overwrite)
    __shared__ __align__(16) char pool[16384 + 9216];
    f16* Ht   = (f16*)pool;
    f16* Ws   = (f16*)(pool + 16384);
    f16* Hout = (f16*)pool;
    __shared__ f16 Ms2[64 * MS_S];
    __shared__ f16 BasI[128 * BI_S];
    __shared__ f16 BasF[32 * BF_S];
    __shared__ float bls[64];
    int t = threadIdx.x;
    int b = blockIdx.x / GPB;
    int g = blockIdx.x % GPB;
    f16* hbase = h + (((size_t)(b * 64)) << 13);
    int lane = t & 63, wv = t >> 6;
    int q = lane >> 4, l15 = lane & 15;

    // ---- tile-invariant staging
    if (t >= 128) {
        int t2 = t - 128;
        // Ws [o][i] fp16 (pre-converted): 32 halfs per thread
        {
            int o = t2 & 63, hs = (t2 >> 6) * 32;
            const f16* src = Wl_h + o * 64 + hs;
            f16* dst = &Ws[o * WS_S + hs];
#pragma unroll
            for (int u = 0; u < 4; ++u) *(f16x8*)&dst[8 * u] = *(const f16x8*)&src[8 * u];
        }
        // Ms2 [o][j]: 16 halfs per thread
        {
            int o = t2 >> 1, seg = (t2 & 1) * 16;
            const f16* src = Mph + b * 2048 + o * 32 + seg;
            f16* dst = &Ms2[o * MS_S + seg];
            *(f16x8*)&dst[0] = *(const f16x8*)&src[0];
            *(f16x8*)&dst[8] = *(const f16x8*)&src[8];
        }
    }
    if (t < 64) bls[t] = bl[t];

    f16x8 Bw[4][2], Bm[4];                     // register-resident across tiles
    f32x4 sacc[2] = {{0.f,0.f,0.f,0.f},{0.f,0.f,0.f,0.f}};

    for (int tile = 0; tile < TILES; ++tile) {
        int n0 = (g * TILES + tile) << 7;
        f16* hbt = hbase + n0;

        if (t < 128) {
            // ---- transpose-stage Ht[n][i] from global h[i][n] (8x8 blocks)
            int ig = t >> 4, nb = t & 15;
            int i0 = ig << 3, ns = nb << 3;
            f16x8 R[8];
#pragma unroll
            for (int k = 0; k < 8; ++k)
                R[k] = *(const f16x8*)(hbt + ((size_t)(i0 + k) << 13) + ns);
            const u32* rd = (const u32*)R;
            int swz = nb & 7;
#pragma unroll
            for (int j = 0; j < 8; ++j) {
                u32 o[4] __attribute__((aligned(16)));
                u32 sel = (j & 1) ? 0x07060302u : 0x05040100u;
                int jd = j >> 1;
#pragma unroll
                for (int e = 0; e < 4; ++e)
                    o[e] = __builtin_amdgcn_perm(rd[(2 * e + 1) * 4 + jd],
                                                 rd[(2 * e) * 4 + jd], sel);
                int col = i0 ^ ((j ^ swz) << 3);
                *(f16x8*)&Ht[(ns + j) * HT_S + col] = *(const f16x8*)o;
            }
        } else {
            int t2 = t - 128;
            // BasI [n][j]: one row per thread (per tile)
            {
                const f16* src = basI_g + (size_t)(n0 + t2) * 32;
                f16* dst = &BasI[t2 * BI_S];
#pragma unroll
                for (int u = 0; u < 4; ++u) *(f16x8*)&dst[8 * u] = *(const f16x8*)&src[8 * u];
            }
            // BasF [km][n] (per tile)
            if (DO_DFT) {
                int km = t2 >> 2, seg = (t2 & 3) * 32;
                const f16* src = basF_g + km * NN + n0 + seg;
                f16* dst = &BasF[km * BF_S + seg];
#pragma unroll
                for (int u = 0; u < 4; ++u) *(f16x8*)&dst[8 * u] = *(const f16x8*)&src[8 * u];
            }
        }
        __syncthreads();

        if (tile == 0) {
            // ---- B-frags: Ws (conv) and Ms2 (irfft) -> registers
#pragma unroll
            for (int ct = 0; ct < 4; ++ct) {
#pragma unroll
                for (int ks = 0; ks < 2; ++ks)
                    Bw[ct][ks] = *(const f16x8*)&Ws[(ct * 16 + l15) * WS_S + ks * 32 + q * 8];
                Bm[ct] = *(const f16x8*)&Ms2[(ct * 16 + l15) * MS_S + q * 8];
            }
        }

        f32x4 acc[4][2];
#pragma unroll
        for (int ct = 0; ct < 4; ++ct)
#pragma unroll
            for (int m = 0; m < 2; ++m) acc[ct][m] = (f32x4){0.f, 0.f, 0.f, 0.f};

#pragma unroll
        for (int mtl = 0; mtl < 2; ++mtl) {
            int nrow = (2 * wv + mtl) * 16 + l15;
            const f16* hrow = &Ht[nrow * HT_S];
            int g3 = ht_swz(nrow);
            // conv: D[n][o] += h^T[n][i] . W[o][i], K=64
#pragma unroll
            for (int ks = 0; ks < 2; ++ks) {
                f16x8 Ah = *(const f16x8*)&hrow[(ks * 32 + q * 8) ^ g3];
#pragma unroll
                for (int ct = 0; ct < 4; ++ct)
                    acc[ct][mtl] = __builtin_amdgcn_mfma_f32_16x16x32_f16(
                        Ah, Bw[ct][ks], acc[ct][mtl], 0, 0, 0);
            }
            // irfft: D[n][o] += BasI[n][j] . Ms2[o][j], K=32
            f16x8 Ab = *(const f16x8*)&BasI[nrow * BI_S + q * 8];
#pragma unroll
            for (int ct = 0; ct < 4; ++ct)
                acc[ct][mtl] = __builtin_amdgcn_mfma_f32_16x16x32_f16(
                    Ab, Bm[ct], acc[ct][mtl], 0, 0, 0);
        }

        // ---- epilogue: bias + fast exact-erf GELU -> Hout[o][n] (aliases Ht)
        float bv[4];
#pragma unroll
        for (int ct = 0; ct < 4; ++ct) bv[ct] = bls[ct * 16 + l15];
        __syncthreads();   // all Ht reads complete before overwrite
#pragma unroll
        for (int ct = 0; ct < 4; ++ct) {
            int o = ct * 16 + l15;
#pragma unroll
            for (int mtl = 0; mtl < 2; ++mtl) {
                int nbase = (2 * wv + mtl) * 16 + q * 4;
                float gg[4];
#pragma unroll
                for (int r = 0; r < 4; ++r)
                    gg[r] = gelu_f(acc[ct][mtl][r] + bv[ct]);
                f16x2 lo = __builtin_bit_cast(f16x2, __builtin_amdgcn_cvt_pkrtz(gg[0], gg[1]));
                f16x2 hi = __builtin_bit_cast(f16x2, __builtin_amdgcn_cvt_pkrtz(gg[2], gg[3]));
                f16x4 pk = {lo[0], lo[1], hi[0], hi[1]};
                *(f16x4*)&Hout[o * HO_S + nbase] = pk;
            }
        }
        __syncthreads();

        if (DO_DFT) {
            dft_accum(Hout, BasF, sacc, lane, wv);
            // h store (coalesced b128)
#pragma unroll
            for (int r = 0; r < 4; ++r) {
                int o = (t >> 4) + 16 * r;
                int ns = (t & 15) << 3;
                *(f16x8*)(hbt + ((size_t)o << 13) + ns) = *(f16x8*)&Hout[o * HO_S + ns];
            }
        } else {
            // projection: out[b][n] = q_b + sum_o q_w[o]*h[o][n]
            if (t < 128) {
                int n = t;
                float s = q_b[0];
#pragma unroll 8
                for (int o = 0; o < 64; ++o) s += q_w[o] * (float)Hout[o * HO_S + n];
                out[(b << 13) + n0 + n] = s;
            }
        }
        if (tile != TILES - 1) __syncthreads();  // Hout reads done before next transpose
    }
    if (DO_DFT) dft_flush(sacc, S, b, lane, wv);
}

// ---------------------------------------------------------------- launch
extern "C" void kernel_launch(void* const* d_in, const int* in_sizes, int n_in,
                              void* d_out, int out_size, void* d_ws, size_t ws_size,
                              hipStream_t stream) {
    const float* x     = (const float*)d_in[0];
    const float* p_w   = (const float*)d_in[1];
    const float* p_b   = (const float*)d_in[2];
    const float* sc_wr = (const float*)d_in[3];
    const float* sc_wi = (const float*)d_in[4];
    const float* w_w   = (const float*)d_in[5];
    const float* w_b   = (const float*)d_in[6];
    const float* q_w   = (const float*)d_in[7];
    const float* q_b   = (const float*)d_in[8];
    float* out = (float*)d_out;

    char* ws = (char*)d_ws;
    f16*   h    = (f16*)ws;                               // 67,108,864 B
    float* S    = (float*)(ws + 67108864ull);             // 524,288 B
    f16*   Mph  = (f16*)(ws + 67633152ull);               // 262,144 B
    f16*   basF = (f16*)(ws + 67895296ull);               // 524,288 B
    f16*   basI = (f16*)(ws + 68419584ull);               // 524,288 B
    f16*   Wh   = (f16*)(ws + 68943872ull);               // 32,768 B

    hipLaunchKernelGGL(fill_basis, dim3(NN / 256), dim3(256), 0, stream,
                       basF, basI, w_w, Wh, S);
    hipLaunchKernelGGL(lift_kernel, dim3(BB * 32), dim3(256), 0, stream,
                       x, p_w, p_b, h, basF, S);
    for (int l = 0; l < 4; ++l) {
        hipLaunchKernelGGL(mode_mix, dim3(BB), dim3(1024), 0, stream,
                           S, sc_wr + l * 65536, sc_wi + l * 65536, Mph);
        if (l < 3) {
            hipLaunchKernelGGL((layer_kernel<1>), dim3(BB * 32), dim3(256), 0, stream,
                               h, Wh + l * 4096, w_b + l * 64, Mph, basF, basI, S,
                               q_w, q_b, out);
        } else {
            hipLaunchKernelGGL((layer_kernel<0>), dim3(BB * 64), dim3(256), 0, stream,
                               h, Wh + l * 4096, w_b + l * 64, Mph, basF, basI, S,
                               q_w, q_b, out);
        }
    }
}